// Round 2
// baseline (184.939 us; speedup 1.0000x reference)
//
#include <hip/hip_runtime.h>
#include <math.h>

// Problem constants
static constexpr int N    = 8192;
static constexpr int DIM  = 512;
static constexpr int DK   = 128;
static constexpr int DV   = 128;
static constexpr float SLOPE = 0.01f;

// Scan partitioning: 256 chunks of 32 (fills the 256-CU grid)
static constexpr int NCH  = 256;
static constexpr int CHSZ = 32;
static constexpr int NCOL = 258;   // 128 (e1*v) + 128 (e2*v) + z1 + z2

// ---------------------------------------------------------------------------
// K1: u_src = W^T a[:DK], u_dst = W^T a[DK:], c = b.a   (double)
// grid 4 x 128 threads; block b owns dims [b*128, b*128+128); coalesced rows.
// ---------------------------------------------------------------------------
__global__ void k_prep(const float* __restrict__ W, const float* __restrict__ b,
                       const float* __restrict__ a,
                       double* __restrict__ u_src, double* __restrict__ u_dst,
                       double* __restrict__ cvals) {
    int dim = blockIdx.x * 128 + threadIdx.x;
    double us = 0.0, ud = 0.0;
#pragma unroll 4
    for (int k = 0; k < DK; ++k) {
        double w = (double)W[(size_t)k * DIM + dim];
        us += w * (double)a[k];
        ud += w * (double)a[DK + k];
    }
    u_src[dim] = us;
    u_dst[dim] = ud;
    if (blockIdx.x == 0) {
        __shared__ double sb0[DK], sb1[DK];
        int t = threadIdx.x;
        sb0[t] = (double)b[t] * (double)a[t];
        sb1[t] = (double)b[t] * (double)a[DK + t];
        __syncthreads();
        if (t == 0) {
            double c0 = 0.0, c1 = 0.0;
            for (int k = 0; k < DK; ++k) { c0 += sb0[k]; c1 += sb1[k]; }
            cvals[0] = c0; cvals[1] = c1;
        }
    }
}

// ---------------------------------------------------------------------------
// K2: s_src[i] = x[i].u_src + c0 ; s_dst[i] = x[i].u_dst + c1
// one wave per row, 4 rows per block
// ---------------------------------------------------------------------------
__global__ void k_s(const float* __restrict__ x,
                    const double* __restrict__ u_src, const double* __restrict__ u_dst,
                    const double* __restrict__ cvals,
                    float* __restrict__ s_src, float* __restrict__ s_dst) {
    int wave = threadIdx.x >> 6;
    int lane = threadIdx.x & 63;
    int row  = blockIdx.x * 4 + wave;
    const float* xr = x + (size_t)row * DIM;
    float xv[8];
    *reinterpret_cast<float4*>(&xv[0]) = *reinterpret_cast<const float4*>(xr + lane * 8);
    *reinterpret_cast<float4*>(&xv[4]) = *reinterpret_cast<const float4*>(xr + lane * 8 + 4);
    double as = 0.0, ad = 0.0;
#pragma unroll
    for (int t = 0; t < 8; ++t) {
        int d = lane * 8 + t;
        double xd = (double)xv[t];
        as += xd * u_src[d];
        ad += xd * u_dst[d];
    }
#pragma unroll
    for (int off = 32; off > 0; off >>= 1) {
        as += __shfl_down(as, off);
        ad += __shfl_down(ad, off);
    }
    if (lane == 0) {
        s_src[row] = (float)(as + cvals[0]);
        s_dst[row] = (float)(ad + cvals[1]);
    }
}

// ---------------------------------------------------------------------------
// K3: v = x @ Wv^T + bv  [N, DV] fp32. 64x64 tile, BK=64, 4x4/thread,
// register double-buffer prefetch of the next k-tile.
// ---------------------------------------------------------------------------
static constexpr int BM = 64;
static constexpr int BN = 64;
static constexpr int BK = 64;
static constexpr int LDP = BK + 4;

__global__ __launch_bounds__(256) void k_v(const float* __restrict__ x,
                                           const float* __restrict__ Wv,
                                           const float* __restrict__ bv,
                                           float* __restrict__ v) {
    __shared__ __align__(16) float xs[BM][LDP];
    __shared__ __align__(16) float wvs[BN][LDP];
    int tid  = threadIdx.x;
    int row0 = blockIdx.x * BM;
    int col0 = blockIdx.y * BN;
    int tx = tid & 15, ty = tid >> 4;

    float acc[4][4];
#pragma unroll
    for (int r = 0; r < 4; ++r)
#pragma unroll
        for (int c = 0; c < 4; ++c) acc[r][c] = 0.0f;

    // prefetch registers: 4 float4 of x, 4 of Wv per thread
    float4 px[4], pw[4];
    int fr[4], fc[4];
#pragma unroll
    for (int i = 0; i < 4; ++i) {
        int f = tid + i * 256;
        fr[i] = f >> 4;
        fc[i] = (f & 15) * 4;
    }
#pragma unroll
    for (int i = 0; i < 4; ++i) {
        px[i] = *reinterpret_cast<const float4*>(x  + (size_t)(row0 + fr[i]) * DIM + fc[i]);
        pw[i] = *reinterpret_cast<const float4*>(Wv + (size_t)(col0 + fr[i]) * DIM + fc[i]);
    }

    for (int t = 0; t < DIM / BK; ++t) {
#pragma unroll
        for (int i = 0; i < 4; ++i) {
            *reinterpret_cast<float4*>(&xs[fr[i]][fc[i]])  = px[i];
            *reinterpret_cast<float4*>(&wvs[fr[i]][fc[i]]) = pw[i];
        }
        __syncthreads();
        if (t < DIM / BK - 1) {
            int kc = (t + 1) * BK;
#pragma unroll
            for (int i = 0; i < 4; ++i) {
                px[i] = *reinterpret_cast<const float4*>(x  + (size_t)(row0 + fr[i]) * DIM + kc + fc[i]);
                pw[i] = *reinterpret_cast<const float4*>(Wv + (size_t)(col0 + fr[i]) * DIM + kc + fc[i]);
            }
        }
        for (int k4 = 0; k4 < BK; k4 += 4) {
            float4 ar[4], br[4];
#pragma unroll
            for (int r = 0; r < 4; ++r)
                ar[r] = *reinterpret_cast<const float4*>(&xs[ty * 4 + r][k4]);
#pragma unroll
            for (int c = 0; c < 4; ++c)
                br[c] = *reinterpret_cast<const float4*>(&wvs[tx + 16 * c][k4]);
#pragma unroll
            for (int r = 0; r < 4; ++r)
#pragma unroll
                for (int c = 0; c < 4; ++c) {
                    acc[r][c] += ar[r].x * br[c].x + ar[r].y * br[c].y +
                                 ar[r].z * br[c].z + ar[r].w * br[c].w;
                }
        }
        __syncthreads();
    }
#pragma unroll
    for (int r = 0; r < 4; ++r) {
        int row = row0 + ty * 4 + r;
#pragma unroll
        for (int c = 0; c < 4; ++c) {
            int col = col0 + tx + 16 * c;
            v[(size_t)row * DV + col] = acc[r][c] + bv[col];
        }
    }
}

// ---------------------------------------------------------------------------
// K4: rank each s_dst value, atomic-free. 512 blocks; block owns 16 j's,
// scans all 8192 i's from an LDS copy; 16 partials per j reduced in LDS.
// ---------------------------------------------------------------------------
__global__ __launch_bounds__(256) void k_count(const float* __restrict__ s_dst,
                                               int* __restrict__ rank) {
    __shared__ __align__(16) float sd[N];
    __shared__ int part[256];
    int tid = threadIdx.x;
    for (int t = tid; t < N / 4; t += 256)
        reinterpret_cast<float4*>(sd)[t] = reinterpret_cast<const float4*>(s_dst)[t];
    __syncthreads();
    int j0  = blockIdx.x * 16;
    int jj  = tid >> 4;          // 0..15
    int seg = tid & 15;          // 0..15
    int j   = j0 + jj;
    float dj = sd[j];
    int cnt = 0;
    const float4* sdv = reinterpret_cast<const float4*>(sd);
    int cbase = seg * 128;       // 128 float4 per segment
    for (int c = 0; c < 128; ++c) {
        float4 q = sdv[cbase + c];
        int i0 = (cbase + c) * 4;
        cnt += (q.x < dj || (q.x == dj && (i0 + 0) < j));
        cnt += (q.y < dj || (q.y == dj && (i0 + 1) < j));
        cnt += (q.z < dj || (q.z == dj && (i0 + 2) < j));
        cnt += (q.w < dj || (q.w == dj && (i0 + 3) < j));
    }
    part[tid] = cnt;
    __syncthreads();
    if (tid < 16) {
        int s = 0;
#pragma unroll
        for (int t = 0; t < 16; ++t) s += part[tid * 16 + t];
        rank[j0 + tid] = s;
    }
}

__global__ void k_scatter(const float* __restrict__ s_dst, const int* __restrict__ rank,
                          float* __restrict__ d_sorted, int* __restrict__ perm) {
    int j = blockIdx.x * 256 + threadIdx.x;
    int r = rank[j];
    d_sorted[r] = s_dst[j];
    perm[r] = j;
}

// ---------------------------------------------------------------------------
// K5a: per-chunk totals of [e1*v | e2*v | z1 | z2] (double). 256 blocks.
// ---------------------------------------------------------------------------
__global__ void k_chunk_tot(const float* __restrict__ d_sorted, const int* __restrict__ perm,
                            const float* __restrict__ v, double* __restrict__ chunk_tot) {
    int ch = blockIdx.x, tid = threadIdx.x;
    __shared__ float e1s[CHSZ], e2s[CHSZ];
    __shared__ int pk[CHSZ];
    float dmax = d_sorted[N - 1];
    if (tid < CHSZ) {
        float d = d_sorted[ch * CHSZ + tid];
        e1s[tid] = expf(d - dmax);
        e2s[tid] = expf(SLOPE * d);
        pk[tid]  = perm[ch * CHSZ + tid];
    }
    __syncthreads();
    int col = tid & 127;
    bool isP2 = tid >= 128;
    double acc = 0.0;
    for (int k = 0; k < CHSZ; ++k) {
        float e = isP2 ? e2s[k] : e1s[k];
        acc += (double)e * (double)v[(size_t)pk[k] * DV + col];
    }
    chunk_tot[(size_t)ch * NCOL + tid] = acc;
    if (tid == 0) {
        double z = 0.0;
        for (int k = 0; k < CHSZ; ++k) z += (double)e1s[k];
        chunk_tot[(size_t)ch * NCOL + 256] = z;
    }
    if (tid == 1) {
        double z = 0.0;
        for (int k = 0; k < CHSZ; ++k) z += (double)e2s[k];
        chunk_tot[(size_t)ch * NCOL + 257] = z;
    }
}

// K5b: parallel cross-chunk exclusive scan. One block per column (258 blocks),
// 256 threads = 256 chunks, LDS Hillis-Steele inclusive scan.
__global__ void k_chunk_off(const double* __restrict__ chunk_tot, double* __restrict__ chunk_off,
                            double* __restrict__ totals) {
    __shared__ double s[256];
    int col = blockIdx.x;
    int tid = threadIdx.x;
    double val = chunk_tot[(size_t)tid * NCOL + col];
    s[tid] = val;
    __syncthreads();
    for (int off = 1; off < 256; off <<= 1) {
        double t = (tid >= off) ? s[tid - off] : 0.0;
        __syncthreads();
        s[tid] += t;
        __syncthreads();
    }
    chunk_off[(size_t)tid * NCOL + col] = s[tid] - val;   // exclusive
    if (tid == 255) totals[col] = s[255];
}

// K5c: within-chunk exclusive scans -> P1, P2 (float), pz1/pz2 (double)
__global__ void k_scan(const float* __restrict__ d_sorted, const int* __restrict__ perm,
                       const float* __restrict__ v, const double* __restrict__ chunk_off,
                       float* __restrict__ P1, float* __restrict__ P2,
                       double* __restrict__ pz1, double* __restrict__ pz2) {
    int ch = blockIdx.x, tid = threadIdx.x;
    __shared__ float e1s[CHSZ], e2s[CHSZ];
    __shared__ int pk[CHSZ];
    float dmax = d_sorted[N - 1];
    if (tid < CHSZ) {
        float d = d_sorted[ch * CHSZ + tid];
        e1s[tid] = expf(d - dmax);
        e2s[tid] = expf(SLOPE * d);
        pk[tid]  = perm[ch * CHSZ + tid];
    }
    __syncthreads();
    int col = tid & 127;
    bool isP2 = tid >= 128;
    float* P = isP2 ? P2 : P1;
    double acc = chunk_off[(size_t)ch * NCOL + tid];
    for (int k = 0; k < CHSZ; ++k) {
        int kg = ch * CHSZ + k;
        P[(size_t)kg * DV + col] = (float)acc;
        float e = isP2 ? e2s[k] : e1s[k];
        acc += (double)e * (double)v[(size_t)pk[k] * DV + col];
    }
    if (tid == 0) {
        double z = chunk_off[(size_t)ch * NCOL + 256];
        for (int k = 0; k < CHSZ; ++k) { pz1[ch * CHSZ + k] = z; z += (double)e1s[k]; }
    }
    if (tid == 1) {
        double z = chunk_off[(size_t)ch * NCOL + 257];
        for (int k = 0; k < CHSZ; ++k) { pz2[ch * CHSZ + k] = z; z += (double)e2s[k]; }
    }
}

// ---------------------------------------------------------------------------
// K6: finalize. 1024 blocks x 256 thr; 8 rows/block; searches hoisted.
// ---------------------------------------------------------------------------
__global__ __launch_bounds__(256) void k_final(const float* __restrict__ s_src,
                                               const float* __restrict__ d_sorted,
                                               const float* __restrict__ P1,
                                               const float* __restrict__ P2,
                                               const double* __restrict__ pz1,
                                               const double* __restrict__ pz2,
                                               const double* __restrict__ totals,
                                               float* __restrict__ out) {
    __shared__ int ski[8];
    __shared__ float ssi[8];
    int tid = threadIdx.x;
    int rbase = blockIdx.x * 8;
    if (tid < 8) {
        int row = rbase + tid;
        float si = s_src[row];
        float thr = -si;
        int lo = 0, hi = N;
        while (lo < hi) {
            int mid = (lo + hi) >> 1;
            if (d_sorted[mid] <= thr) lo = mid + 1; else hi = mid;
        }
        ski[tid] = lo;
        ssi[tid] = si;
    }
    __syncthreads();
    float dmax = d_sorted[N - 1];
    int dv = tid & 127;
    int half = tid >> 7;                 // 0 or 1
    double T1 = totals[dv];
    double T2 = totals[128 + dv];
    double z1T = totals[256], z2T = totals[257];
#pragma unroll
    for (int it = 0; it < 4; ++it) {
        int r2 = it * 2 + half;
        int row = rbase + r2;
        float si = ssi[r2];
        int ki = ski[r2];
        float t = si + dmax;
        float m = t > 0.0f ? t : SLOPE * t;
        float alpha = expf(t - m);
        float beta  = expf(SLOPE * si - m);
        double suf1, sufz1, pre2, prez2;
        if (ki < N) {
            suf1  = T1 - (double)P1[(size_t)ki * DV + dv];
            sufz1 = z1T - pz1[ki];
            pre2  = (double)P2[(size_t)ki * DV + dv];
            prez2 = pz2[ki];
        } else {
            suf1 = 0.0; sufz1 = 0.0; pre2 = T2; prez2 = z2T;
        }
        double num = (double)alpha * suf1  + (double)beta * pre2;
        double den = (double)alpha * sufz1 + (double)beta * prez2;
        out[(size_t)row * DV + dv] = (float)(num / den);
    }
}

// ---------------------------------------------------------------------------
extern "C" void kernel_launch(void* const* d_in, const int* in_sizes, int n_in,
                              void* d_out, int out_size, void* d_ws, size_t ws_size,
                              hipStream_t stream) {
    const float* x  = (const float*)d_in[0];
    const float* W  = (const float*)d_in[1];
    const float* b  = (const float*)d_in[2];
    const float* Wv = (const float*)d_in[3];
    const float* bv = (const float*)d_in[4];
    const float* a  = (const float*)d_in[5];
    float* out = (float*)d_out;

    char* base = (char*)d_ws;
    size_t off = 0;
    auto carve = [&](size_t bytes) -> void* {
        void* p = base + off;
        off = (off + bytes + 255) & ~(size_t)255;
        return p;
    };
    double* u_src     = (double*)carve(DIM * sizeof(double));
    double* u_dst     = (double*)carve(DIM * sizeof(double));
    double* cvals     = (double*)carve(2 * sizeof(double));
    float*  s_src     = (float*)carve(N * sizeof(float));
    float*  s_dst     = (float*)carve(N * sizeof(float));
    float*  d_sorted  = (float*)carve(N * sizeof(float));
    int*    perm      = (int*)carve(N * sizeof(int));
    int*    rank      = (int*)carve(N * sizeof(int));
    double* pz1       = (double*)carve(N * sizeof(double));
    double* pz2       = (double*)carve(N * sizeof(double));
    double* chunk_tot = (double*)carve((size_t)NCH * NCOL * sizeof(double));
    double* chunk_off = (double*)carve((size_t)NCH * NCOL * sizeof(double));
    double* totals    = (double*)carve(NCOL * sizeof(double));
    float*  P1        = (float*)carve((size_t)N * DV * sizeof(float));
    float*  P2        = (float*)carve((size_t)N * DV * sizeof(float));
    float*  v         = out;  // d_out doubles as the v buffer (dead before k_final writes)

    k_prep<<<4, 128, 0, stream>>>(W, b, a, u_src, u_dst, cvals);
    k_s<<<N / 4, 256, 0, stream>>>(x, u_src, u_dst, cvals, s_src, s_dst);
    k_v<<<dim3(N / BM, DV / BN), 256, 0, stream>>>(x, Wv, bv, v);
    k_count<<<N / 16, 256, 0, stream>>>(s_dst, rank);
    k_scatter<<<N / 256, 256, 0, stream>>>(s_dst, rank, d_sorted, perm);
    k_chunk_tot<<<NCH, 256, 0, stream>>>(d_sorted, perm, v, chunk_tot);
    k_chunk_off<<<NCOL, 256, 0, stream>>>(chunk_tot, chunk_off, totals);
    k_scan<<<NCH, 256, 0, stream>>>(d_sorted, perm, v, chunk_off, P1, P2, pz1, pz2);
    k_final<<<N / 8, 256, 0, stream>>>(s_src, d_sorted, P1, P2, pz1, pz2, totals, out);
}

// Round 4
// 169.328 us; speedup vs baseline: 1.0922x; 1.0922x over previous
//
#include <hip/hip_runtime.h>
#include <math.h>

// Problem constants
static constexpr int N    = 8192;
static constexpr int DIM  = 512;
static constexpr int DK   = 128;
static constexpr int DV   = 128;
static constexpr float SLOPE = 0.01f;

// Scan partitioning
static constexpr int NCH  = 256;
static constexpr int CHSZ = 32;
static constexpr int NCOL = 258;   // 128 (e1*v) + 128 (e2*v) + z1 + z2

// k_v geometry: BM=128 x BN=128 tile, 8x8 per thread, split-K chosen at launch
static constexpr int MT  = 128;
static constexpr int BK  = 32;
static constexpr int LDT = 132;    // padded LDS row stride (16B-aligned rows, 2-way max on reads)

// ---------------------------------------------------------------------------
// K1 fused front: per block compute u_src/u_dst = W^T a halves (redundant, in
// padded LDS) + c0/c1 = b.a halves, then s_src/s_dst for 32 rows. 256 blocks.
// ---------------------------------------------------------------------------
__global__ __launch_bounds__(256) void k_front(const float* __restrict__ x,
                                               const float* __restrict__ W,
                                               const float* __restrict__ b,
                                               const float* __restrict__ a,
                                               float* __restrict__ s_src,
                                               float* __restrict__ s_dst) {
    __shared__ float sa[2 * DK];
    __shared__ float sus[DIM + 32], sud[DIM + 32];  // idx d -> d + (d>>6)*4
    __shared__ float sc[2];
    int tid = threadIdx.x;
    sa[tid] = a[tid];
    __syncthreads();

    {   // c0/c1: wave 0 reduces b.a[:128], wave 1 reduces b.a[128:]
        float p = 0.0f;
        if (tid < 64)        p = b[tid] * sa[tid] + b[tid + 64] * sa[tid + 64];
        else if (tid < 128) { int l = tid - 64; p = b[l] * sa[DK + l] + b[l + 64] * sa[DK + 64 + l]; }
#pragma unroll
        for (int off = 32; off > 0; off >>= 1) p += __shfl_down(p, off);
        if (tid == 0)  sc[0] = p;
        if (tid == 64) sc[1] = p;
    }

#pragma unroll
    for (int half = 0; half < 2; ++half) {
        int d = tid + half * 256;
        float us = 0.0f, ud = 0.0f;
#pragma unroll 4
        for (int k = 0; k < DK; ++k) {
            float w = W[(size_t)k * DIM + d];
            us += w * sa[k];
            ud += w * sa[DK + k];
        }
        int dp = d + (d >> 6) * 4;
        sus[dp] = us;
        sud[dp] = ud;
    }
    __syncthreads();

    int r   = tid >> 3;
    int seg = tid & 7;
    int row = blockIdx.x * 32 + r;
    const float* xr = x + (size_t)row * DIM;
    int base  = seg * 64;
    int baseP = base + seg * 4;
    float accs = 0.0f, accd = 0.0f;
#pragma unroll
    for (int i = 0; i < 16; ++i) {
        float4 q  = *reinterpret_cast<const float4*>(xr + base + i * 4);
        float4 u4 = *reinterpret_cast<const float4*>(&sus[baseP + i * 4]);
        float4 w4 = *reinterpret_cast<const float4*>(&sud[baseP + i * 4]);
        accs += q.x * u4.x + q.y * u4.y + q.z * u4.z + q.w * u4.w;
        accd += q.x * w4.x + q.y * w4.y + q.z * w4.z + q.w * w4.w;
    }
#pragma unroll
    for (int off = 4; off > 0; off >>= 1) {
        accs += __shfl_down(accs, off);
        accd += __shfl_down(accd, off);
    }
    if (seg == 0) {
        s_src[row] = accs + sc[0];
        s_dst[row] = accd + sc[1];
    }
}

// ---------------------------------------------------------------------------
// K2: v partials. grid = 64 m-tiles x ksplit, 256 threads. BM=BN=128, 8x8
// thread tile, A/B transposed in LDS ([BK][LDT]) -> conflict-free b128 reads.
// ---------------------------------------------------------------------------
__global__ __launch_bounds__(256) void k_v(const float* __restrict__ x,
                                           const float* __restrict__ Wv,
                                           float* __restrict__ vpart, int ksplit) {
    __shared__ float At[BK][LDT];
    __shared__ float Bt[BK][LDT];
    int tid = threadIdx.x;
    int mt  = blockIdx.x & 63;
    int ks  = blockIdx.x >> 6;
    int row0 = mt * MT;
    int ksub = DIM / ksplit;
    int kb0  = ks * ksub;
    int nt   = ksub / BK;
    int tx = tid & 15, ty = tid >> 4;

    float acc[8][8];
#pragma unroll
    for (int i = 0; i < 8; ++i)
#pragma unroll
        for (int j = 0; j < 8; ++j) acc[i][j] = 0.0f;

    int fr[4], fk[4];
#pragma unroll
    for (int i = 0; i < 4; ++i) {
        int f = tid + i * 256;
        fr[i] = f >> 3;          // 0..127
        fk[i] = (f & 7) * 4;     // 0,4,..,28
    }
    float4 px[4], pw[4];
#pragma unroll
    for (int i = 0; i < 4; ++i) {
        px[i] = *reinterpret_cast<const float4*>(x  + (size_t)(row0 + fr[i]) * DIM + kb0 + fk[i]);
        pw[i] = *reinterpret_cast<const float4*>(Wv + (size_t)fr[i] * DIM + kb0 + fk[i]);
    }

    for (int t = 0; t < nt; ++t) {
#pragma unroll
        for (int i = 0; i < 4; ++i) {
            At[fk[i] + 0][fr[i]] = px[i].x;
            At[fk[i] + 1][fr[i]] = px[i].y;
            At[fk[i] + 2][fr[i]] = px[i].z;
            At[fk[i] + 3][fr[i]] = px[i].w;
            Bt[fk[i] + 0][fr[i]] = pw[i].x;
            Bt[fk[i] + 1][fr[i]] = pw[i].y;
            Bt[fk[i] + 2][fr[i]] = pw[i].z;
            Bt[fk[i] + 3][fr[i]] = pw[i].w;
        }
        __syncthreads();
        if (t < nt - 1) {
            int kb = kb0 + (t + 1) * BK;
#pragma unroll
            for (int i = 0; i < 4; ++i) {
                px[i] = *reinterpret_cast<const float4*>(x  + (size_t)(row0 + fr[i]) * DIM + kb + fk[i]);
                pw[i] = *reinterpret_cast<const float4*>(Wv + (size_t)fr[i] * DIM + kb + fk[i]);
            }
        }
#pragma unroll 4
        for (int kk = 0; kk < BK; ++kk) {
            float4 a0 = *reinterpret_cast<const float4*>(&At[kk][ty * 4]);
            float4 a1 = *reinterpret_cast<const float4*>(&At[kk][64 + ty * 4]);
            float4 b0 = *reinterpret_cast<const float4*>(&Bt[kk][tx * 4]);
            float4 b1 = *reinterpret_cast<const float4*>(&Bt[kk][64 + tx * 4]);
            float av[8] = {a0.x, a0.y, a0.z, a0.w, a1.x, a1.y, a1.z, a1.w};
            float bw[8] = {b0.x, b0.y, b0.z, b0.w, b1.x, b1.y, b1.z, b1.w};
#pragma unroll
            for (int i = 0; i < 8; ++i)
#pragma unroll
                for (int j = 0; j < 8; ++j) acc[i][j] += av[i] * bw[j];
        }
        __syncthreads();
    }

#pragma unroll
    for (int rh = 0; rh < 2; ++rh)
#pragma unroll
        for (int i = 0; i < 4; ++i) {
            int row = row0 + rh * 64 + ty * 4 + i;
            float* dst = vpart + ((size_t)ks * N + row) * DV;
#pragma unroll
            for (int ch = 0; ch < 2; ++ch) {
                float4 o;
                o.x = acc[rh * 4 + i][ch * 4 + 0];
                o.y = acc[rh * 4 + i][ch * 4 + 1];
                o.z = acc[rh * 4 + i][ch * 4 + 2];
                o.w = acc[rh * 4 + i][ch * 4 + 3];
                *reinterpret_cast<float4*>(dst + ch * 64 + tx * 4) = o;
            }
        }
}

// K2b: reduce ksplit partials + bias -> v. 1024 blocks x 256 thr.
__global__ void k_vred(const float* __restrict__ vpart, const float* __restrict__ bv,
                       float* __restrict__ v, int ksplit) {
    int fi = blockIdx.x * 256 + threadIdx.x;
    const float4* vp = reinterpret_cast<const float4*>(vpart);
    float4 s = vp[fi];
    for (int ksp = 1; ksp < ksplit; ++ksp) {
        float4 q = vp[(size_t)ksp * (N * DV / 4) + fi];
        s.x += q.x; s.y += q.y; s.z += q.z; s.w += q.w;
    }
    float4 bb = reinterpret_cast<const float4*>(bv)[fi & 31];
    s.x += bb.x; s.y += bb.y; s.z += bb.z; s.w += bb.w;
    reinterpret_cast<float4*>(v)[fi] = s;
}

// ---------------------------------------------------------------------------
// K3: rank + scatter fused. 512 blocks; block owns 16 j's, full s_dst in LDS.
// ---------------------------------------------------------------------------
__global__ __launch_bounds__(256) void k_rank_scatter(const float* __restrict__ s_dst,
                                                      float* __restrict__ d_sorted,
                                                      int* __restrict__ perm) {
    __shared__ __align__(16) float sd[N];
    __shared__ int part[256];
    int tid = threadIdx.x;
    for (int t = tid; t < N / 4; t += 256)
        reinterpret_cast<float4*>(sd)[t] = reinterpret_cast<const float4*>(s_dst)[t];
    __syncthreads();
    int j0  = blockIdx.x * 16;
    int jj  = tid >> 4;
    int seg = tid & 15;
    int j   = j0 + jj;
    float dj = sd[j];
    int cnt = 0;
    const float4* sdv = reinterpret_cast<const float4*>(sd);
    int cbase = seg * 128;
    for (int c = 0; c < 128; ++c) {
        float4 q = sdv[cbase + c];
        int i0 = (cbase + c) * 4;
        cnt += (q.x < dj || (q.x == dj && (i0 + 0) < j));
        cnt += (q.y < dj || (q.y == dj && (i0 + 1) < j));
        cnt += (q.z < dj || (q.z == dj && (i0 + 2) < j));
        cnt += (q.w < dj || (q.w == dj && (i0 + 3) < j));
    }
    part[tid] = cnt;
    __syncthreads();
    if (tid < 16) {
        int s = 0;
#pragma unroll
        for (int t = 0; t < 16; ++t) s += part[tid * 16 + t];
        int jw = j0 + tid;
        d_sorted[s] = sd[jw];
        perm[s] = jw;
    }
}

// ---------------------------------------------------------------------------
// K4a: per-chunk totals of [e1*v | e2*v | z1 | z2] (double). 256 blocks.
// ---------------------------------------------------------------------------
__global__ void k_chunk_tot(const float* __restrict__ d_sorted, const int* __restrict__ perm,
                            const float* __restrict__ v, double* __restrict__ chunk_tot) {
    int ch = blockIdx.x, tid = threadIdx.x;
    __shared__ float e1s[CHSZ], e2s[CHSZ];
    __shared__ int pk[CHSZ];
    float dmax = d_sorted[N - 1];
    if (tid < CHSZ) {
        float d = d_sorted[ch * CHSZ + tid];
        e1s[tid] = expf(d - dmax);
        e2s[tid] = expf(SLOPE * d);
        pk[tid]  = perm[ch * CHSZ + tid];
    }
    __syncthreads();
    int col = tid & 127;
    bool isP2 = tid >= 128;
    double acc = 0.0;
    for (int k = 0; k < CHSZ; ++k) {
        float e = isP2 ? e2s[k] : e1s[k];
        acc += (double)e * (double)v[(size_t)pk[k] * DV + col];
    }
    chunk_tot[(size_t)ch * NCOL + tid] = acc;
    if (tid == 0) {
        double z = 0.0;
        for (int k = 0; k < CHSZ; ++k) z += (double)e1s[k];
        chunk_tot[(size_t)ch * NCOL + 256] = z;
    }
    if (tid == 1) {
        double z = 0.0;
        for (int k = 0; k < CHSZ; ++k) z += (double)e2s[k];
        chunk_tot[(size_t)ch * NCOL + 257] = z;
    }
}

// K4b: cross-chunk exclusive scan. 258 blocks x 256 thr (Hillis-Steele).
__global__ void k_chunk_off(const double* __restrict__ chunk_tot, double* __restrict__ chunk_off,
                            double* __restrict__ totals) {
    __shared__ double s[256];
    int col = blockIdx.x;
    int tid = threadIdx.x;
    double val = chunk_tot[(size_t)tid * NCOL + col];
    s[tid] = val;
    __syncthreads();
    for (int off = 1; off < 256; off <<= 1) {
        double t = (tid >= off) ? s[tid - off] : 0.0;
        __syncthreads();
        s[tid] += t;
        __syncthreads();
    }
    chunk_off[(size_t)tid * NCOL + col] = s[tid] - val;   // exclusive
    if (tid == 255) totals[col] = s[255];
}

// K4c: within-chunk exclusive scans -> P1, P2 (float), pz1/pz2 (double)
__global__ void k_scan(const float* __restrict__ d_sorted, const int* __restrict__ perm,
                       const float* __restrict__ v, const double* __restrict__ chunk_off,
                       float* __restrict__ P1, float* __restrict__ P2,
                       double* __restrict__ pz1, double* __restrict__ pz2) {
    int ch = blockIdx.x, tid = threadIdx.x;
    __shared__ float e1s[CHSZ], e2s[CHSZ];
    __shared__ int pk[CHSZ];
    float dmax = d_sorted[N - 1];
    if (tid < CHSZ) {
        float d = d_sorted[ch * CHSZ + tid];
        e1s[tid] = expf(d - dmax);
        e2s[tid] = expf(SLOPE * d);
        pk[tid]  = perm[ch * CHSZ + tid];
    }
    __syncthreads();
    int col = tid & 127;
    bool isP2 = tid >= 128;
    float* P = isP2 ? P2 : P1;
    double acc = chunk_off[(size_t)ch * NCOL + tid];
    for (int k = 0; k < CHSZ; ++k) {
        int kg = ch * CHSZ + k;
        P[(size_t)kg * DV + col] = (float)acc;
        float e = isP2 ? e2s[k] : e1s[k];
        acc += (double)e * (double)v[(size_t)pk[k] * DV + col];
    }
    if (tid == 0) {
        double z = chunk_off[(size_t)ch * NCOL + 256];
        for (int k = 0; k < CHSZ; ++k) { pz1[ch * CHSZ + k] = z; z += (double)e1s[k]; }
    }
    if (tid == 1) {
        double z = chunk_off[(size_t)ch * NCOL + 257];
        for (int k = 0; k < CHSZ; ++k) { pz2[ch * CHSZ + k] = z; z += (double)e2s[k]; }
    }
}

// ---------------------------------------------------------------------------
// K5: finalize. 1024 blocks x 256 thr; 8 rows/block; searches hoisted.
// ---------------------------------------------------------------------------
__global__ __launch_bounds__(256) void k_final(const float* __restrict__ s_src,
                                               const float* __restrict__ d_sorted,
                                               const float* __restrict__ P1,
                                               const float* __restrict__ P2,
                                               const double* __restrict__ pz1,
                                               const double* __restrict__ pz2,
                                               const double* __restrict__ totals,
                                               float* __restrict__ out) {
    __shared__ int ski[8];
    __shared__ float ssi[8];
    int tid = threadIdx.x;
    int rbase = blockIdx.x * 8;
    if (tid < 8) {
        int row = rbase + tid;
        float si = s_src[row];
        float thr = -si;
        int lo = 0, hi = N;
        while (lo < hi) {
            int mid = (lo + hi) >> 1;
            if (d_sorted[mid] <= thr) lo = mid + 1; else hi = mid;
        }
        ski[tid] = lo;
        ssi[tid] = si;
    }
    __syncthreads();
    float dmax = d_sorted[N - 1];
    int dv = tid & 127;
    int half = tid >> 7;
    double T1 = totals[dv];
    double T2 = totals[128 + dv];
    double z1T = totals[256], z2T = totals[257];
#pragma unroll
    for (int it = 0; it < 4; ++it) {
        int r2 = it * 2 + half;
        int row = rbase + r2;
        float si = ssi[r2];
        int ki = ski[r2];
        float t = si + dmax;
        float m = t > 0.0f ? t : SLOPE * t;
        float alpha = expf(t - m);
        float beta  = expf(SLOPE * si - m);
        double suf1, sufz1, pre2, prez2;
        if (ki < N) {
            suf1  = T1 - (double)P1[(size_t)ki * DV + dv];
            sufz1 = z1T - pz1[ki];
            pre2  = (double)P2[(size_t)ki * DV + dv];
            prez2 = pz2[ki];
        } else {
            suf1 = 0.0; sufz1 = 0.0; pre2 = T2; prez2 = z2T;
        }
        double num = (double)alpha * suf1  + (double)beta * pre2;
        double den = (double)alpha * sufz1 + (double)beta * prez2;
        out[(size_t)row * DV + dv] = (float)(num / den);
    }
}

// ---------------------------------------------------------------------------
extern "C" void kernel_launch(void* const* d_in, const int* in_sizes, int n_in,
                              void* d_out, int out_size, void* d_ws, size_t ws_size,
                              hipStream_t stream) {
    const float* x  = (const float*)d_in[0];
    const float* W  = (const float*)d_in[1];
    const float* b  = (const float*)d_in[2];
    const float* Wv = (const float*)d_in[3];
    const float* bv = (const float*)d_in[4];
    const float* a  = (const float*)d_in[5];
    float* out = (float*)d_out;

    char* base = (char*)d_ws;
    size_t off = 0;
    auto carve = [&](size_t bytes) -> void* {
        void* p = base + off;
        off = (off + bytes + 255) & ~(size_t)255;
        return p;
    };
    float*  s_src     = (float*)carve(N * sizeof(float));
    float*  s_dst     = (float*)carve(N * sizeof(float));
    float*  d_sorted  = (float*)carve(N * sizeof(float));
    int*    perm      = (int*)carve(N * sizeof(int));
    double* pz1       = (double*)carve(N * sizeof(double));
    double* pz2       = (double*)carve(N * sizeof(double));
    double* chunk_tot = (double*)carve((size_t)NCH * NCOL * sizeof(double));
    double* chunk_off = (double*)carve((size_t)NCH * NCOL * sizeof(double));
    double* totals    = (double*)carve(NCOL * sizeof(double));

    // Union region: vpart (ksplit * 4 MB, dead after k_vred) aliases
    // P1/P2 (8 MB, written later in k_scan). ksplit adapts to ws_size so we
    // NEVER exceed the workspace (round-3 failure suspect: unchecked 50 MB).
    const size_t planeB = (size_t)N * DV * sizeof(float);   // 4 MB
    size_t avail = ws_size > off ? ws_size - off : 0;
    int ksplit = 2;
    if (avail >= 8 * planeB + 4096)      ksplit = 8;
    else if (avail >= 4 * planeB + 4096) ksplit = 4;
    size_t unionBytes = (size_t)(ksplit > 2 ? ksplit : 2) * planeB;
    char* uni = (char*)carve(unionBytes);
    float* vpart = (float*)uni;
    float* P1    = (float*)uni;
    float* P2    = (float*)(uni + planeB);
    float* v     = out;   // d_out doubles as v (dead before k_final writes)

    k_front<<<N / 32, 256, 0, stream>>>(x, W, b, a, s_src, s_dst);
    k_v<<<64 * ksplit, 256, 0, stream>>>(x, Wv, vpart, ksplit);
    k_vred<<<N * DV / 4 / 256, 256, 0, stream>>>(vpart, bv, v, ksplit);
    k_rank_scatter<<<N / 16, 256, 0, stream>>>(s_dst, d_sorted, perm);
    k_chunk_tot<<<NCH, 256, 0, stream>>>(d_sorted, perm, v, chunk_tot);
    k_chunk_off<<<NCOL, 256, 0, stream>>>(chunk_tot, chunk_off, totals);
    k_scan<<<NCH, 256, 0, stream>>>(d_sorted, perm, v, chunk_off, P1, P2, pz1, pz2);
    k_final<<<N / 8, 256, 0, stream>>>(s_src, d_sorted, P1, P2, pz1, pz2, totals, out);
}

// Round 5
// 169.112 us; speedup vs baseline: 1.0936x; 1.0013x over previous
//
#include <hip/hip_runtime.h>
#include <math.h>

// Problem constants
static constexpr int N    = 8192;
static constexpr int DIM  = 512;
static constexpr int DK   = 128;
static constexpr int DV   = 128;
static constexpr float SLOPE = 0.01f;

// Scan partitioning: 512 chunks of 16 sorted rows
static constexpr int NCH  = 512;
static constexpr int CHSZ = 16;
static constexpr int NCOL = 258;   // 128 (Y1 cols) + 128 (Y2 cols) + z1 + z2

// k_v geometry: BM=128 x BN=128 tile, 8x8 per thread, split-K chosen at launch
static constexpr int MT  = 128;
static constexpr int BK  = 32;
static constexpr int LDT = 132;    // padded LDS row stride

// ---------------------------------------------------------------------------
// K1 fused front: per block compute u_src/u_dst = W^T a halves (redundant, in
// padded LDS) + c0/c1 = b.a halves, then s_src/s_dst for 32 rows. 256 blocks.
// ---------------------------------------------------------------------------
__global__ __launch_bounds__(256) void k_front(const float* __restrict__ x,
                                               const float* __restrict__ W,
                                               const float* __restrict__ b,
                                               const float* __restrict__ a,
                                               float* __restrict__ s_src,
                                               float* __restrict__ s_dst) {
    __shared__ float sa[2 * DK];
    __shared__ float sus[DIM + 32], sud[DIM + 32];  // idx d -> d + (d>>6)*4
    __shared__ float sc[2];
    int tid = threadIdx.x;
    sa[tid] = a[tid];
    __syncthreads();

    {   // c0/c1: wave 0 reduces b.a[:128], wave 1 reduces b.a[128:]
        float p = 0.0f;
        if (tid < 64)        p = b[tid] * sa[tid] + b[tid + 64] * sa[tid + 64];
        else if (tid < 128) { int l = tid - 64; p = b[l] * sa[DK + l] + b[l + 64] * sa[DK + 64 + l]; }
#pragma unroll
        for (int off = 32; off > 0; off >>= 1) p += __shfl_down(p, off);
        if (tid == 0)  sc[0] = p;
        if (tid == 64) sc[1] = p;
    }

#pragma unroll
    for (int half = 0; half < 2; ++half) {
        int d = tid + half * 256;
        float us = 0.0f, ud = 0.0f;
#pragma unroll 4
        for (int k = 0; k < DK; ++k) {
            float w = W[(size_t)k * DIM + d];
            us += w * sa[k];
            ud += w * sa[DK + k];
        }
        int dp = d + (d >> 6) * 4;
        sus[dp] = us;
        sud[dp] = ud;
    }
    __syncthreads();

    int r   = tid >> 3;
    int seg = tid & 7;
    int row = blockIdx.x * 32 + r;
    const float* xr = x + (size_t)row * DIM;
    int base  = seg * 64;
    int baseP = base + seg * 4;
    float accs = 0.0f, accd = 0.0f;
#pragma unroll
    for (int i = 0; i < 16; ++i) {
        float4 q  = *reinterpret_cast<const float4*>(xr + base + i * 4);
        float4 u4 = *reinterpret_cast<const float4*>(&sus[baseP + i * 4]);
        float4 w4 = *reinterpret_cast<const float4*>(&sud[baseP + i * 4]);
        accs += q.x * u4.x + q.y * u4.y + q.z * u4.z + q.w * u4.w;
        accd += q.x * w4.x + q.y * w4.y + q.z * w4.z + q.w * w4.w;
    }
#pragma unroll
    for (int off = 4; off > 0; off >>= 1) {
        accs += __shfl_down(accs, off);
        accd += __shfl_down(accd, off);
    }
    if (seg == 0) {
        s_src[row] = accs + sc[0];
        s_dst[row] = accd + sc[1];
    }
}

// ---------------------------------------------------------------------------
// K2: v partials. grid = 64 m-tiles x ksplit, 256 threads. BM=BN=128, 8x8
// thread tile, A/B transposed in LDS ([BK][LDT]) -> conflict-free b128 reads.
// ---------------------------------------------------------------------------
__global__ __launch_bounds__(256) void k_v(const float* __restrict__ x,
                                           const float* __restrict__ Wv,
                                           float* __restrict__ vpart, int ksplit) {
    __shared__ float At[BK][LDT];
    __shared__ float Bt[BK][LDT];
    int tid = threadIdx.x;
    int mt  = blockIdx.x & 63;
    int ks  = blockIdx.x >> 6;
    int row0 = mt * MT;
    int ksub = DIM / ksplit;
    int kb0  = ks * ksub;
    int nt   = ksub / BK;
    int tx = tid & 15, ty = tid >> 4;

    float acc[8][8];
#pragma unroll
    for (int i = 0; i < 8; ++i)
#pragma unroll
        for (int j = 0; j < 8; ++j) acc[i][j] = 0.0f;

    int fr[4], fk[4];
#pragma unroll
    for (int i = 0; i < 4; ++i) {
        int f = tid + i * 256;
        fr[i] = f >> 3;          // 0..127
        fk[i] = (f & 7) * 4;     // 0,4,..,28
    }
    float4 px[4], pw[4];
#pragma unroll
    for (int i = 0; i < 4; ++i) {
        px[i] = *reinterpret_cast<const float4*>(x  + (size_t)(row0 + fr[i]) * DIM + kb0 + fk[i]);
        pw[i] = *reinterpret_cast<const float4*>(Wv + (size_t)fr[i] * DIM + kb0 + fk[i]);
    }

    for (int t = 0; t < nt; ++t) {
#pragma unroll
        for (int i = 0; i < 4; ++i) {
            At[fk[i] + 0][fr[i]] = px[i].x;
            At[fk[i] + 1][fr[i]] = px[i].y;
            At[fk[i] + 2][fr[i]] = px[i].z;
            At[fk[i] + 3][fr[i]] = px[i].w;
            Bt[fk[i] + 0][fr[i]] = pw[i].x;
            Bt[fk[i] + 1][fr[i]] = pw[i].y;
            Bt[fk[i] + 2][fr[i]] = pw[i].z;
            Bt[fk[i] + 3][fr[i]] = pw[i].w;
        }
        __syncthreads();
        if (t < nt - 1) {
            int kb = kb0 + (t + 1) * BK;
#pragma unroll
            for (int i = 0; i < 4; ++i) {
                px[i] = *reinterpret_cast<const float4*>(x  + (size_t)(row0 + fr[i]) * DIM + kb + fk[i]);
                pw[i] = *reinterpret_cast<const float4*>(Wv + (size_t)fr[i] * DIM + kb + fk[i]);
            }
        }
#pragma unroll 4
        for (int kk = 0; kk < BK; ++kk) {
            float4 a0 = *reinterpret_cast<const float4*>(&At[kk][ty * 4]);
            float4 a1 = *reinterpret_cast<const float4*>(&At[kk][64 + ty * 4]);
            float4 b0 = *reinterpret_cast<const float4*>(&Bt[kk][tx * 4]);
            float4 b1 = *reinterpret_cast<const float4*>(&Bt[kk][64 + tx * 4]);
            float av[8] = {a0.x, a0.y, a0.z, a0.w, a1.x, a1.y, a1.z, a1.w};
            float bw[8] = {b0.x, b0.y, b0.z, b0.w, b1.x, b1.y, b1.z, b1.w};
#pragma unroll
            for (int i = 0; i < 8; ++i)
#pragma unroll
                for (int j = 0; j < 8; ++j) acc[i][j] += av[i] * bw[j];
        }
        __syncthreads();
    }

#pragma unroll
    for (int rh = 0; rh < 2; ++rh)
#pragma unroll
        for (int i = 0; i < 4; ++i) {
            int row = row0 + rh * 64 + ty * 4 + i;
            float* dst = vpart + ((size_t)ks * N + row) * DV;
#pragma unroll
            for (int ch = 0; ch < 2; ++ch) {
                float4 o;
                o.x = acc[rh * 4 + i][ch * 4 + 0];
                o.y = acc[rh * 4 + i][ch * 4 + 1];
                o.z = acc[rh * 4 + i][ch * 4 + 2];
                o.w = acc[rh * 4 + i][ch * 4 + 3];
                *reinterpret_cast<float4*>(dst + ch * 64 + tx * 4) = o;
            }
        }
}

// ---------------------------------------------------------------------------
// K3: rank + scatter fused. 512 blocks; block owns 16 j's, full s_dst in LDS.
// ---------------------------------------------------------------------------
__global__ __launch_bounds__(256) void k_rank_scatter(const float* __restrict__ s_dst,
                                                      float* __restrict__ d_sorted,
                                                      int* __restrict__ perm) {
    __shared__ __align__(16) float sd[N];
    __shared__ int part[256];
    int tid = threadIdx.x;
    for (int t = tid; t < N / 4; t += 256)
        reinterpret_cast<float4*>(sd)[t] = reinterpret_cast<const float4*>(s_dst)[t];
    __syncthreads();
    int j0  = blockIdx.x * 16;
    int jj  = tid >> 4;
    int seg = tid & 15;
    int j   = j0 + jj;
    float dj = sd[j];
    int cnt = 0;
    const float4* sdv = reinterpret_cast<const float4*>(sd);
    int cbase = seg * 128;
    for (int c = 0; c < 128; ++c) {
        float4 q = sdv[cbase + c];
        int i0 = (cbase + c) * 4;
        cnt += (q.x < dj || (q.x == dj && (i0 + 0) < j));
        cnt += (q.y < dj || (q.y == dj && (i0 + 1) < j));
        cnt += (q.z < dj || (q.z == dj && (i0 + 2) < j));
        cnt += (q.w < dj || (q.w == dj && (i0 + 3) < j));
    }
    part[tid] = cnt;
    __syncthreads();
    if (tid < 16) {
        int s = 0;
#pragma unroll
        for (int t = 0; t < 16; ++t) s += part[tid * 16 + t];
        int jw = j0 + tid;
        d_sorted[s] = sd[jw];
        perm[s] = jw;
    }
}

// ---------------------------------------------------------------------------
// K4: fused vred + permute + scale + chunk totals. 512 blocks x 16 sorted rows.
// For sorted pos r: j=perm[r]; vrow = sum_ksp vpart[ksp][j] + bv;
// Y1[r]=e1*vrow, Y2[r]=e2*vrow (coalesced); chunk totals via LDS (double).
// ---------------------------------------------------------------------------
__global__ __launch_bounds__(256) void k_vredY(const float* __restrict__ vpart,
                                               const float* __restrict__ bv,
                                               const float* __restrict__ d_sorted,
                                               const int* __restrict__ perm,
                                               float* __restrict__ Y1,
                                               float* __restrict__ Y2,
                                               double* __restrict__ chunk_tot,
                                               int ksplit) {
    __shared__ float sv[CHSZ][DV];    // unscaled vrows
    __shared__ float se1[CHSZ], se2[CHSZ];
    int ch  = blockIdx.x;
    int tid = threadIdx.x;
    int g   = tid >> 5;               // 0..7 row subgroup
    int c4  = tid & 31;               // float4 col
    float dmax = d_sorted[N - 1];
    if (tid < CHSZ) {
        float d = d_sorted[ch * CHSZ + tid];
        se1[tid] = expf(d - dmax);
        se2[tid] = expf(SLOPE * d);
    }
    __syncthreads();
    float4 bb = reinterpret_cast<const float4*>(bv)[c4];
#pragma unroll
    for (int half = 0; half < 2; ++half) {
        int rl = half * 8 + g;
        int r  = ch * CHSZ + rl;
        int j  = perm[r];
        float4 s = {0.f, 0.f, 0.f, 0.f};
        for (int ksp = 0; ksp < ksplit; ++ksp) {
            float4 q = *reinterpret_cast<const float4*>(vpart + ((size_t)ksp * N + j) * DV + c4 * 4);
            s.x += q.x; s.y += q.y; s.z += q.z; s.w += q.w;
        }
        s.x += bb.x; s.y += bb.y; s.z += bb.z; s.w += bb.w;
        *reinterpret_cast<float4*>(&sv[rl][c4 * 4]) = s;
        float e1 = se1[rl], e2 = se2[rl];
        float4 o1 = {e1 * s.x, e1 * s.y, e1 * s.z, e1 * s.w};
        float4 o2 = {e2 * s.x, e2 * s.y, e2 * s.z, e2 * s.w};
        *reinterpret_cast<float4*>(Y1 + (size_t)r * DV + c4 * 4) = o1;
        *reinterpret_cast<float4*>(Y2 + (size_t)r * DV + c4 * 4) = o2;
    }
    __syncthreads();
    // chunk totals: col threads accumulate over 16 rows (float product, double sum)
    int col = tid & 127;
    bool is2 = tid >= 128;
    double acc = 0.0;
#pragma unroll
    for (int k = 0; k < CHSZ; ++k) {
        float e = is2 ? se2[k] : se1[k];
        acc += (double)(e * sv[k][col]);
    }
    chunk_tot[(size_t)ch * NCOL + tid] = acc;
    if (tid == 0) {
        double z = 0.0;
#pragma unroll
        for (int k = 0; k < CHSZ; ++k) z += (double)se1[k];
        chunk_tot[(size_t)ch * NCOL + 256] = z;
    }
    if (tid == 1) {
        double z = 0.0;
#pragma unroll
        for (int k = 0; k < CHSZ; ++k) z += (double)se2[k];
        chunk_tot[(size_t)ch * NCOL + 257] = z;
    }
}

// ---------------------------------------------------------------------------
// K5: cross-chunk exclusive scan over 512 chunks. 258 blocks x 256 thr;
// each thread owns chunk pair (2t, 2t+1); Hillis-Steele over pair sums.
// ---------------------------------------------------------------------------
__global__ __launch_bounds__(256) void k_coff(const double* __restrict__ chunk_tot,
                                              double* __restrict__ chunk_off,
                                              double* __restrict__ totals) {
    __shared__ double sp[256];
    int col = blockIdx.x;
    int tid = threadIdx.x;
    double v0 = chunk_tot[(size_t)(2 * tid) * NCOL + col];
    double v1 = chunk_tot[(size_t)(2 * tid + 1) * NCOL + col];
    double p = v0 + v1;
    sp[tid] = p;
    __syncthreads();
    for (int off = 1; off < 256; off <<= 1) {
        double t = (tid >= off) ? sp[tid - off] : 0.0;
        __syncthreads();
        sp[tid] += t;
        __syncthreads();
    }
    double excl = sp[tid] - p;
    chunk_off[(size_t)(2 * tid) * NCOL + col]     = excl;
    chunk_off[(size_t)(2 * tid + 1) * NCOL + col] = excl + v0;
    if (tid == 255) totals[col] = sp[255];
}

// ---------------------------------------------------------------------------
// K6: within-chunk exclusive scans over contiguous Y -> P1, P2 (float),
// pz1/pz2 (double). 512 blocks; fully coalesced loads/stores.
// ---------------------------------------------------------------------------
__global__ __launch_bounds__(256) void k_scanW(const float* __restrict__ Y1,
                                               const float* __restrict__ Y2,
                                               const float* __restrict__ d_sorted,
                                               const double* __restrict__ chunk_off,
                                               float* __restrict__ P1,
                                               float* __restrict__ P2,
                                               double* __restrict__ pz1,
                                               double* __restrict__ pz2) {
    int ch  = blockIdx.x;
    int tid = threadIdx.x;
    int col = tid & 127;
    bool is2 = tid >= 128;
    const float* Y = is2 ? Y2 : Y1;
    float* P       = is2 ? P2 : P1;
    double acc = chunk_off[(size_t)ch * NCOL + tid];
#pragma unroll
    for (int k = 0; k < CHSZ; ++k) {
        size_t idx = (size_t)(ch * CHSZ + k) * DV + col;
        P[idx] = (float)acc;
        acc += (double)Y[idx];
    }
    if (tid < 2) {
        float dmax = d_sorted[N - 1];
        double z = chunk_off[(size_t)ch * NCOL + 256 + tid];
        double* pz = tid == 0 ? pz1 : pz2;
#pragma unroll
        for (int k = 0; k < CHSZ; ++k) {
            int r = ch * CHSZ + k;
            float d = d_sorted[r];
            float e = (tid == 0) ? expf(d - dmax) : expf(SLOPE * d);
            pz[r] = z;
            z += (double)e;
        }
    }
}

// ---------------------------------------------------------------------------
// K7: finalize. 1024 blocks x 256 thr; 8 rows/block; searches hoisted.
// ---------------------------------------------------------------------------
__global__ __launch_bounds__(256) void k_final(const float* __restrict__ s_src,
                                               const float* __restrict__ d_sorted,
                                               const float* __restrict__ P1,
                                               const float* __restrict__ P2,
                                               const double* __restrict__ pz1,
                                               const double* __restrict__ pz2,
                                               const double* __restrict__ totals,
                                               float* __restrict__ out) {
    __shared__ int ski[8];
    __shared__ float ssi[8];
    int tid = threadIdx.x;
    int rbase = blockIdx.x * 8;
    if (tid < 8) {
        int row = rbase + tid;
        float si = s_src[row];
        float thr = -si;
        int lo = 0, hi = N;
        while (lo < hi) {
            int mid = (lo + hi) >> 1;
            if (d_sorted[mid] <= thr) lo = mid + 1; else hi = mid;
        }
        ski[tid] = lo;
        ssi[tid] = si;
    }
    __syncthreads();
    float dmax = d_sorted[N - 1];
    int dv = tid & 127;
    int half = tid >> 7;
    double T1 = totals[dv];
    double T2 = totals[128 + dv];
    double z1T = totals[256], z2T = totals[257];
#pragma unroll
    for (int it = 0; it < 4; ++it) {
        int r2 = it * 2 + half;
        int row = rbase + r2;
        float si = ssi[r2];
        int ki = ski[r2];
        float t = si + dmax;
        float m = t > 0.0f ? t : SLOPE * t;
        float alpha = expf(t - m);
        float beta  = expf(SLOPE * si - m);
        double suf1, sufz1, pre2, prez2;
        if (ki < N) {
            suf1  = T1 - (double)P1[(size_t)ki * DV + dv];
            sufz1 = z1T - pz1[ki];
            pre2  = (double)P2[(size_t)ki * DV + dv];
            prez2 = pz2[ki];
        } else {
            suf1 = 0.0; sufz1 = 0.0; pre2 = T2; prez2 = z2T;
        }
        double num = (double)alpha * suf1  + (double)beta * pre2;
        double den = (double)alpha * sufz1 + (double)beta * prez2;
        out[(size_t)row * DV + dv] = (float)(num / den);
    }
}

// ---------------------------------------------------------------------------
extern "C" void kernel_launch(void* const* d_in, const int* in_sizes, int n_in,
                              void* d_out, int out_size, void* d_ws, size_t ws_size,
                              hipStream_t stream) {
    const float* x  = (const float*)d_in[0];
    const float* W  = (const float*)d_in[1];
    const float* b  = (const float*)d_in[2];
    const float* Wv = (const float*)d_in[3];
    const float* bv = (const float*)d_in[4];
    const float* a  = (const float*)d_in[5];
    float* out = (float*)d_out;

    char* base = (char*)d_ws;
    size_t off = 0;
    auto carve = [&](size_t bytes) -> void* {
        void* p = base + off;
        off = (off + bytes + 255) & ~(size_t)255;
        return p;
    };
    float*  s_src     = (float*)carve(N * sizeof(float));
    float*  s_dst     = (float*)carve(N * sizeof(float));
    float*  d_sorted  = (float*)carve(N * sizeof(float));
    int*    perm      = (int*)carve(N * sizeof(int));
    double* pz1       = (double*)carve(N * sizeof(double));
    double* pz2       = (double*)carve(N * sizeof(double));
    double* chunk_tot = (double*)carve((size_t)NCH * NCOL * sizeof(double));
    double* chunk_off = (double*)carve((size_t)NCH * NCOL * sizeof(double));
    double* totals    = (double*)carve(NCOL * sizeof(double));
    float*  Y1        = (float*)carve((size_t)N * DV * sizeof(float));
    float*  Y2        = (float*)carve((size_t)N * DV * sizeof(float));

    // Union region: vpart (ksplit * 4 MB, dead after k_vredY) aliases
    // P1/P2 (8 MB, written later in k_scanW). ksplit adapts to ws_size.
    const size_t planeB = (size_t)N * DV * sizeof(float);   // 4 MB
    size_t avail = ws_size > off ? ws_size - off : 0;
    int ksplit = 2;
    if (avail >= 8 * planeB + 4096)      ksplit = 8;
    else if (avail >= 4 * planeB + 4096) ksplit = 4;
    size_t unionBytes = (size_t)(ksplit > 2 ? ksplit : 2) * planeB;
    char* uni = (char*)carve(unionBytes);
    float* vpart = (float*)uni;
    float* P1    = (float*)uni;
    float* P2    = (float*)(uni + planeB);

    k_front<<<N / 32, 256, 0, stream>>>(x, W, b, a, s_src, s_dst);
    k_v<<<64 * ksplit, 256, 0, stream>>>(x, Wv, vpart, ksplit);
    k_rank_scatter<<<N / 16, 256, 0, stream>>>(s_dst, d_sorted, perm);
    k_vredY<<<NCH, 256, 0, stream>>>(vpart, bv, d_sorted, perm, Y1, Y2, chunk_tot, ksplit);
    k_coff<<<NCOL, 256, 0, stream>>>(chunk_tot, chunk_off, totals);
    k_scanW<<<NCH, 256, 0, stream>>>(Y1, Y2, d_sorted, chunk_off, P1, P2, pz1, pz2);
    k_final<<<N / 8, 256, 0, stream>>>(s_src, d_sorted, P1, P2, pz1, pz2, totals, out);
}